// Round 1
// baseline (379.688 us; speedup 1.0000x reference)
//
#include <hip/hip_runtime.h>
#include <math.h>

#define N_NODES 100000
#define N_EDGES 1600000
#define RR      6
#define CIN     8
#define COUT    16
#define EPS     1e-8f

// Workspace layout (floats):
//   z    : N * RR * COUT * 2   (interleaved complex, (n, r, o) row-major)  = 19.2M floats
//   y_re : N * COUT                                                        = 1.6M floats
//   y_im : N * COUT                                                        = 1.6M floats

// ---------------------------------------------------------------------------
// Kernel 1: z[n,r,o] = sum_c x[n,c] * weight[r,c,o] * exp(i*offset[c,o])
// One thread per (n, o); filt staged in LDS once per block.
// ---------------------------------------------------------------------------
__global__ void compute_z_kernel(const float* __restrict__ x,
                                 const float* __restrict__ weight,
                                 const float* __restrict__ offset,
                                 float* __restrict__ z) {
    __shared__ float fre[RR * CIN * COUT];
    __shared__ float fim[RR * CIN * COUT];
    for (int i = threadIdx.x; i < RR * CIN * COUT; i += blockDim.x) {
        int co = i % (CIN * COUT);     // (c*COUT + o) — offset is (CIN, COUT)
        float w   = weight[i];         // weight is (RR, CIN, COUT) row-major == flat i
        float off = offset[co];
        fre[i] = w * cosf(off);
        fim[i] = w * sinf(off);
    }
    __syncthreads();

    int gid = blockIdx.x * blockDim.x + threadIdx.x;
    if (gid >= N_NODES * COUT) return;
    int n = gid / COUT;
    int o = gid % COUT;

    float xv[CIN];
#pragma unroll
    for (int c = 0; c < CIN; ++c) xv[c] = x[n * CIN + c];

    float2* zp = (float2*)z + (size_t)n * RR * COUT + o;
#pragma unroll
    for (int r = 0; r < RR; ++r) {
        float zr = 0.f, zi = 0.f;
#pragma unroll
        for (int c = 0; c < CIN; ++c) {
            int idx = (r * CIN + c) * COUT + o;
            zr = fmaf(xv[c], fre[idx], zr);
            zi = fmaf(xv[c], fim[idx], zi);
        }
        zp[r * COUT] = make_float2(zr, zi);
    }
}

// ---------------------------------------------------------------------------
// Kernel 2: per edge e: y[dst,o] += sum_r sten[e,r] * z[src,r,o]  (complex)
// 16 lanes per edge (lane = o). 2 fp32 atomics per lane into planar y.
// ---------------------------------------------------------------------------
__global__ void edge_kernel(const int* __restrict__ edges,
                            const float* __restrict__ sten,
                            const float* __restrict__ z,
                            float* __restrict__ y_re,
                            float* __restrict__ y_im) {
    unsigned int gid = blockIdx.x * blockDim.x + threadIdx.x;
    if (gid >= (unsigned int)N_EDGES * COUT) return;
    unsigned int e = gid >> 4;
    unsigned int o = gid & 15u;

    int src = edges[2 * e];
    int dst = edges[2 * e + 1];

    const float2* zp = (const float2*)z + (size_t)src * RR * COUT + o;
    const float2* sp = (const float2*)sten + (size_t)e * RR;

    float acc_re = 0.f, acc_im = 0.f;
#pragma unroll
    for (int r = 0; r < RR; ++r) {
        float2 s  = sp[r];            // broadcast across the 16 lanes of this edge
        float2 zv = zp[r * COUT];     // coalesced 128B across the 16 lanes
        acc_re = fmaf(s.x, zv.x, acc_re);
        acc_re = fmaf(-s.y, zv.y, acc_re);
        acc_im = fmaf(s.x, zv.y, acc_im);
        acc_im = fmaf(s.y, zv.x, acc_im);
    }
    atomicAdd(&y_re[(size_t)dst * COUT + o], acc_re);
    atomicAdd(&y_im[(size_t)dst * COUT + o], acc_im);
}

// ---------------------------------------------------------------------------
// Kernel 3: magnitude nonlinearity + interleave to output (N, COUT, 2)
// ---------------------------------------------------------------------------
__global__ void finish_kernel(const float* __restrict__ y_re,
                              const float* __restrict__ y_im,
                              const float* __restrict__ bias,
                              float* __restrict__ out) {
    int gid = blockIdx.x * blockDim.x + threadIdx.x;
    if (gid >= N_NODES * COUT) return;
    int o = gid & 15;
    float re = y_re[gid];
    float im = y_im[gid];
    float mag = sqrtf(re * re + im * im);
    float s = fmaxf(mag + bias[o], 0.f) / (mag + EPS);
    ((float2*)out)[gid] = make_float2(re * s, im * s);
}

extern "C" void kernel_launch(void* const* d_in, const int* in_sizes, int n_in,
                              void* d_out, int out_size, void* d_ws, size_t ws_size,
                              hipStream_t stream) {
    const float* x      = (const float*)d_in[0];
    const int*   edges  = (const int*)d_in[1];
    const float* sten   = (const float*)d_in[2];
    const float* weight = (const float*)d_in[3];
    const float* offset = (const float*)d_in[4];
    const float* bias   = (const float*)d_in[5];
    float* out = (float*)d_out;

    float* z    = (float*)d_ws;                              // 19.2M floats
    float* y_re = z + (size_t)N_NODES * RR * COUT * 2;       // 1.6M floats
    float* y_im = y_re + (size_t)N_NODES * COUT;             // 1.6M floats

    // y must be zeroed every call (ws is re-poisoned to 0xAA before each launch)
    hipMemsetAsync(y_re, 0, sizeof(float) * 2 * (size_t)N_NODES * COUT, stream);

    {
        int total = N_NODES * COUT;
        dim3 grid((total + 255) / 256), block(256);
        compute_z_kernel<<<grid, block, 0, stream>>>(x, weight, offset, z);
    }
    {
        unsigned int total = (unsigned int)N_EDGES * COUT;   // 25.6M threads
        dim3 grid((total + 255) / 256), block(256);
        edge_kernel<<<grid, block, 0, stream>>>(edges, sten, z, y_re, y_im);
    }
    {
        int total = N_NODES * COUT;
        dim3 grid((total + 255) / 256), block(256);
        finish_kernel<<<grid, block, 0, stream>>>(y_re, y_im, bias, out);
    }
}